// Round 2
// baseline (1381.166 us; speedup 1.0000x reference)
//
#include <hip/hip_runtime.h>
#include <math.h>

#define NPTS 4096
#define NBATCH 4
#define BLOCK 1024
#define WAVES 16
#define SEG (NPTS/WAVES)   // 256 columns per wave

static constexpr float KSCALE     = 1.4426950408889634f / 1e-4f;   // log2(e)/eps
static constexpr float EPSLN2     = 1e-4f * 0.6931471805599453f;   // eps*ln(2)
static constexpr float NEGEPSLOGW = 8.31776616671934e-4f;          // -eps * (-log(4096))

__device__ __forceinline__ float fexp2(float x){
#if __has_builtin(__builtin_amdgcn_exp2f)
  return __builtin_amdgcn_exp2f(x);
#else
  return exp2f(x);
#endif
}
__device__ __forceinline__ float flog2(float x){
#if __has_builtin(__builtin_amdgcn_logf)
  return __builtin_amdgcn_logf(x);
#else
  return log2f(x);
#endif
}

// One launch = two independent softmin problems (256 blocks each).
// Block: 1024 thr = 16 waves; 64 rows per block (lane = row), wave = 256-col segment.
// Columns come from a packed float4 array (qx,qy,qz,Atilde) read via wave-uniform
// (scalar) loads. Atilde = (h[m] - 0.5|q_m|^2)*KSCALE was written by the producer
// launch. This kernel writes out[ridx] and the NEXT consumer's pack .w.
__global__ __launch_bounds__(BLOCK, 8) void softmin_kernel(
    const float* __restrict__ rowA, int rsA, const float4* __restrict__ pkInA,
    float4* __restrict__ pkOutA, const float* __restrict__ hOldA,
    float* __restrict__ outA, int modeA,
    const float* __restrict__ rowB, int rsB, const float4* __restrict__ pkInB,
    float4* __restrict__ pkOutB, const float* __restrict__ hOldB,
    float* __restrict__ outB, int modeB)
{
  __shared__ float2 comb[WAVES][64];

  int bid = blockIdx.x;
  const float* rowp; const float4* pkin; float4* pkout; const float* hold;
  float* outp; int rs, mode;
  if (bid < 256) { rowp=rowA; pkin=pkInA; pkout=pkOutA; hold=hOldA; outp=outA; rs=rsA; mode=modeA; }
  else           { rowp=rowB; pkin=pkInB; pkout=pkOutB; hold=hOldB; outp=outB; rs=rsB; mode=modeB; }
  int lb = bid & 255;
  int b = lb >> 6;
  int rowblk = lb & 63;

  int tid = threadIdx.x, lane = tid & 63;
  int wv = __builtin_amdgcn_readfirstlane(tid >> 6);

  int row = rowblk*64 + lane;
  int ridx = b*NPTS + row;
  const float* p = rowp + (size_t)ridx * rs;
  float px = p[0], py = p[1], pz = p[2];
  float chalf = 0.5f*(px*px + py*py + pz*pz);
  float ptx = px*KSCALE, pty = py*KSCALE, ptz = pz*KSCALE;

  const float4* pk = pkin + (b*NPTS + wv*SEG);

  float M = -INFINITY, S = 0.f;
  #pragma unroll 2
  for (int c = 0; c < SEG/8; ++c) {
    const float4 a0 = pk[c*8+0], a1 = pk[c*8+1], a2 = pk[c*8+2], a3 = pk[c*8+3];
    const float4 a4 = pk[c*8+4], a5 = pk[c*8+5], a6 = pk[c*8+6], a7 = pk[c*8+7];
    float t0 = fmaf(ptx, a0.x, fmaf(pty, a0.y, fmaf(ptz, a0.z, a0.w)));
    float t1 = fmaf(ptx, a1.x, fmaf(pty, a1.y, fmaf(ptz, a1.z, a1.w)));
    float t2 = fmaf(ptx, a2.x, fmaf(pty, a2.y, fmaf(ptz, a2.z, a2.w)));
    float t3 = fmaf(ptx, a3.x, fmaf(pty, a3.y, fmaf(ptz, a3.z, a3.w)));
    float t4 = fmaf(ptx, a4.x, fmaf(pty, a4.y, fmaf(ptz, a4.z, a4.w)));
    float t5 = fmaf(ptx, a5.x, fmaf(pty, a5.y, fmaf(ptz, a5.z, a5.w)));
    float t6 = fmaf(ptx, a6.x, fmaf(pty, a6.y, fmaf(ptz, a6.z, a6.w)));
    float t7 = fmaf(ptx, a7.x, fmaf(pty, a7.y, fmaf(ptz, a7.z, a7.w)));
    float Mc = fmaxf(fmaxf(fmaxf(t0,t1), fmaxf(t2,t3)),
                     fmaxf(fmaxf(t4,t5), fmaxf(t6,t7)));
    float Mn = fmaxf(M, Mc);
    float sc = fexp2(M - Mn);
    float e0 = fexp2(t0-Mn) + fexp2(t1-Mn);
    float e1 = fexp2(t2-Mn) + fexp2(t3-Mn);
    float e2 = fexp2(t4-Mn) + fexp2(t5-Mn);
    float e3 = fexp2(t6-Mn) + fexp2(t7-Mn);
    S = fmaf(S, sc, (e0+e1) + (e2+e3));
    M = Mn;
  }

  float2 mys; mys.x = M; mys.y = S;
  comb[wv][lane] = mys;
  __syncthreads();

  if (wv == 0) {
    float2 v[WAVES];
    float Mstar = -INFINITY;
    #pragma unroll
    for (int w = 0; w < WAVES; ++w) { v[w] = comb[w][lane]; Mstar = fmaxf(Mstar, v[w].x); }
    float Ssum = 0.f;
    #pragma unroll
    for (int w = 0; w < WAVES; ++w) Ssum = fmaf(v[w].y, fexp2(v[w].x - Mstar), Ssum);
    float lse2 = Mstar + flog2(Ssum);
    float res = fmaf(-EPSLN2, lse2, chalf + NEGEPSLOGW);
    if (mode) res = 0.5f*(hold[ridx] + res);
    outp[ridx] = res;
    pkout[ridx].w = (res - chalf) * KSCALE;
  }
}

// Build the 6 packed column arrays once per launch. .w gets the h=0 initial Atilde.
__global__ void pack_init(const float* __restrict__ x, const float* __restrict__ y,
                          float4* pkfab, float4* pkgab,
                          float4* pkfaa0, float4* pkfaa1,
                          float4* pkgbb0, float4* pkgbb1)
{
  int i = blockIdx.x*256 + threadIdx.x;        // 0..16383 == b*4096+m
  const float* xp = x + (size_t)i*3;
  float xx = xp[0], xy = xp[1], xz = xp[2];
  float4 vx; vx.x=xx; vx.y=xy; vx.z=xz;
  vx.w = -0.5f*(xx*xx + xy*xy + xz*xz)*KSCALE;
  const float* yp = y + (size_t)i*4;
  float yx = yp[0], yy = yp[1], yz = yp[2];
  float4 vy; vy.x=yx; vy.y=yy; vy.z=yz;
  vy.w = -0.5f*(yx*yx + yy*yy + yz*yz)*KSCALE;
  pkgab[i]  = vx; pkfaa0[i] = vx; pkfaa1[i] = vx;
  pkfab[i]  = vy; pkgbb0[i] = vy; pkgbb1[i] = vy;
}

__global__ void reduce_kernel(const float* __restrict__ fab, const float* __restrict__ faa,
                              const float* __restrict__ gab, const float* __restrict__ gbb,
                              float* __restrict__ out)
{
  int b = blockIdx.x;
  int tid = threadIdx.x;
  float s = 0.f;
  for (int i = tid; i < NPTS; i += 256) {
    int idx = b*NPTS + i;
    s += (fab[idx] - faa[idx]) + (gab[idx] - gbb[idx]);
  }
  for (int off = 32; off > 0; off >>= 1) s += __shfl_down(s, off, 64);
  __shared__ float red[4];
  if ((tid & 63) == 0) red[tid >> 6] = s;
  __syncthreads();
  if (tid == 0) out[b] = (red[0]+red[1]+red[2]+red[3]) * (1.0f/NPTS);
}

extern "C" void kernel_launch(void* const* d_in, const int* in_sizes, int n_in,
                              void* d_out, int out_size, void* d_ws, size_t ws_size,
                              hipStream_t stream)
{
  const float* x = (const float*)d_in[0];   // (4,4096,3)
  const float* y = (const float*)d_in[1];   // (4,4096,4), first 3 comps used
  float* ws = (float*)d_ws;
  const size_t P = (size_t)NBATCH * NPTS;   // 16384

  float* f_ab    = ws + 0*P;
  float* g_ab    = ws + 1*P;
  float* faaR[2] = { ws + 2*P, ws + 4*P };
  float* gbbR[2] = { ws + 3*P, ws + 5*P };
  float4* pk4    = (float4*)(ws + 6*P);
  float4* PKfab    = pk4 + 0*P;             // cols = y, .w = Atilde(g_ab)
  float4* PKgab    = pk4 + 1*P;             // cols = x, .w = Atilde(f_ab)
  float4* PKfaa[2] = { pk4 + 2*P, pk4 + 3*P };
  float4* PKgbb[2] = { pk4 + 4*P, pk4 + 5*P };

  // zero h_old for the first averaged symmetric step (faaR[0], gbbR[0] contiguous)
  hipMemsetAsync(ws + 2*P, 0, 2*P*sizeof(float), stream);
  pack_init<<<dim3(P/256), dim3(256), 0, stream>>>(x, y, PKfab, PKgab,
                                                   PKfaa[0], PKfaa[1], PKgbb[0], PKgbb[1]);

  for (int i = 0; i < 21; ++i) {
    int cur = i & 1, nxt = cur ^ 1;
    int modeS = (i < 20) ? 1 : 0;    // averaged symmetric update except final softmin
    // phase 1: f_ab = softmin over y-cols (Atilde from g_ab)  ||  f_aa step
    softmin_kernel<<<512, BLOCK, 0, stream>>>(
        x, 3, PKfab, PKgab, f_ab, f_ab, 0,
        x, 3, PKfaa[cur], PKfaa[nxt], faaR[cur], faaR[nxt], modeS);
    // phase 2: g_ab = softmin over x-cols (Atilde from f_ab)  ||  g_bb step
    softmin_kernel<<<512, BLOCK, 0, stream>>>(
        y, 4, PKgab, PKfab, g_ab, g_ab, 0,
        y, 4, PKgbb[cur], PKgbb[nxt], gbbR[cur], gbbR[nxt], modeS);
  }
  // i=20 wrote faaR[1]/gbbR[1]
  reduce_kernel<<<dim3(4), dim3(256), 0, stream>>>(f_ab, faaR[1], g_ab, gbbR[1], (float*)d_out);
}